// Round 1
// baseline (1357.197 us; speedup 1.0000x reference)
//
#include <hip/hip_runtime.h>

constexpr int D = 64;
constexpr int NREL = 2;
constexpr int NBASIS = 16;
constexpr int NLAYERS = 3;

// h_r = alpha @ Basis   -> hr[3][64]
__global__ void hr_init_kernel(const float* __restrict__ alpha,
                               const float* __restrict__ basis,
                               float* __restrict__ hr) {
  int t = threadIdx.x;            // 192 threads
  int r = t >> 6, d = t & 63;
  float s = 0.f;
  for (int b = 0; b < NBASIS; ++b) s += alpha[r * NBASIS + b] * basis[b * D + d];
  hr[r * D + d] = s;
}

// h_r = act(h_r @ W_rel.T)
__global__ void hr_update_kernel(const float* __restrict__ hr_in,
                                 const float* __restrict__ Wrel,
                                 float* __restrict__ hr_out, int do_relu) {
  int t = threadIdx.x;            // 192 threads
  int r = t >> 6, d = t & 63;
  float s = 0.f;
  for (int k = 0; k < D; ++k) s += hr_in[r * D + k] * Wrel[d * D + k];
  if (do_relu) s = fmaxf(s, 0.f);
  hr_out[r * D + d] = s;
}

__global__ void hist_kernel(const int* __restrict__ dst, int* __restrict__ cnt, int E) {
  int e = blockIdx.x * blockDim.x + threadIdx.x;
  if (e < E) atomicAdd(&cnt[dst[e]], 1);
}

// single-block exclusive scan of cnt[0..N-1] -> start[0..N], cursor copy
__global__ void scan_kernel(const int* __restrict__ cnt, int* __restrict__ start,
                            int* __restrict__ cursor, int N, int CH) {
  __shared__ int sums[1024];
  int t = threadIdx.x;
  int base = t * CH;
  int s = 0;
  for (int i = 0; i < CH; ++i) {
    int idx = base + i;
    if (idx < N) s += cnt[idx];
  }
  sums[t] = s;
  __syncthreads();
  for (int off = 1; off < 1024; off <<= 1) {
    int v = (t >= off) ? sums[t - off] : 0;
    __syncthreads();
    sums[t] += v;
    __syncthreads();
  }
  int run = (t == 0) ? 0 : sums[t - 1];
  for (int i = 0; i < CH; ++i) {
    int idx = base + i;
    if (idx < N) {
      start[idx] = run;
      cursor[idx] = run;
      run += cnt[idx];
    }
  }
  if (t == 1023) start[N] = run;   // == E
}

// perm[p] = src | et<<17 | dir<<18   (src < 2^17)
__global__ void scatter_kernel(const int* __restrict__ src, const int* __restrict__ dst,
                               const int* __restrict__ et, const int* __restrict__ dir,
                               int* __restrict__ cursor, int* __restrict__ perm, int E) {
  int e = blockIdx.x * blockDim.x + threadIdx.x;
  if (e < E) {
    int t = dst[e];
    int p = atomicAdd(&cursor[t], 1);
    perm[p] = src[e] | (et[e] << 17) | (dir[e] << 18);
  }
}

// wave per node: aggO[v], aggI[v] = sum over in-edges of (h[src]-hr[et]) split by dir
__global__ __launch_bounds__(256) void gather_kernel(
    const float* __restrict__ h, const float* __restrict__ hr,
    const int* __restrict__ start, const int* __restrict__ perm,
    float* __restrict__ aggO, float* __restrict__ aggI, int N) {
  int lane = threadIdx.x & 63;
  int v = blockIdx.x * 4 + (threadIdx.x >> 6);
  if (v >= N) return;
  float hr0 = hr[lane];
  float hr1 = hr[D + lane];
  int beg = start[v], end = start[v + 1];
  float accO = 0.f, accI = 0.f;
  for (int j = beg; j < end; ++j) {
    int p = perm[j];
    int s = p & 0x1FFFF;
    float c = h[(size_t)s * D + lane] - (((p >> 17) & 1) ? hr1 : hr0);
    if (p & (1 << 18)) accI += c; else accO += c;
  }
  aggO[(size_t)v * D + lane] = accO;
  aggI[(size_t)v * D + lane] = accI;
}

// h_out[v] = act((h[v]-hr_self)@WS.T + aggO[v]@WO.T + aggI[v]@WI.T)
// wave computes 8 rows; lane = output dim d; W staged in LDS (pad 17 float4/row,
// stride 272B -> conflict-free ds_read_b128)
__global__ __launch_bounds__(256) void node_kernel(
    const float* __restrict__ h_in, const float* __restrict__ aggO,
    const float* __restrict__ aggI, const float* __restrict__ WS,
    const float* __restrict__ WO, const float* __restrict__ WI,
    const float* __restrict__ hr_self, float* __restrict__ h_out,
    int do_relu, int N) {
  __shared__ float4 lws[64 * 17];
  __shared__ float4 lwo[64 * 17];
  __shared__ float4 lwi[64 * 17];
  int tid = threadIdx.x;
  const float4* gws = (const float4*)WS;
  const float4* gwo = (const float4*)WO;
  const float4* gwi = (const float4*)WI;
  for (int i = tid; i < 1024; i += 256) {
    int d = i >> 4, k4 = i & 15;
    lws[d * 17 + k4] = gws[i];
    lwo[d * 17 + k4] = gwo[i];
    lwi[d * 17 + k4] = gwi[i];
  }
  __syncthreads();
  int lane = tid & 63;
  int wid = blockIdx.x * 4 + (tid >> 6);
  const int R = 8;
  int row0 = wid * R;
  if (row0 >= N) return;
  float acc[R];
#pragma unroll
  for (int r = 0; r < R; ++r) acc[r] = 0.f;
  const float4* hr4 = (const float4*)hr_self;
  for (int k4 = 0; k4 < 16; ++k4) {
    float4 ws4 = lws[lane * 17 + k4];
    float4 wo4 = lwo[lane * 17 + k4];
    float4 wi4 = lwi[lane * 17 + k4];
    float4 hs4 = hr4[k4];
#pragma unroll
    for (int r = 0; r < R; ++r) {
      int row = row0 + r;
      if (row < N) {
        const float4 xh = ((const float4*)(h_in + (size_t)row * D))[k4];
        const float4 xo = ((const float4*)(aggO + (size_t)row * D))[k4];
        const float4 xi = ((const float4*)(aggI + (size_t)row * D))[k4];
        acc[r] += (xh.x - hs4.x) * ws4.x + (xh.y - hs4.y) * ws4.y +
                  (xh.z - hs4.z) * ws4.z + (xh.w - hs4.w) * ws4.w +
                  xo.x * wo4.x + xo.y * wo4.y + xo.z * wo4.z + xo.w * wo4.w +
                  xi.x * wi4.x + xi.y * wi4.y + xi.z * wi4.z + xi.w * wi4.w;
      }
    }
  }
#pragma unroll
  for (int r = 0; r < R; ++r) {
    int row = row0 + r;
    if (row < N) {
      float v = acc[r];
      if (do_relu) v = fmaxf(v, 0.f);
      h_out[(size_t)row * D + lane] = v;
    }
  }
}

extern "C" void kernel_launch(void* const* d_in, const int* in_sizes, int n_in,
                              void* d_out, int out_size, void* d_ws, size_t ws_size,
                              hipStream_t stream) {
  const float* h_u   = (const float*)d_in[0];
  const float* Basis = (const float*)d_in[1];
  const float* alpha = (const float*)d_in[2];
  const float* W_O   = (const float*)d_in[3];
  const float* W_I   = (const float*)d_in[4];
  const float* W_S   = (const float*)d_in[5];
  const float* W_rel = (const float*)d_in[6];
  const int* src  = (const int*)d_in[7];
  const int* dst  = (const int*)d_in[8];
  const int* et   = (const int*)d_in[9];
  const int* edir = (const int*)d_in[10];
  int N = in_sizes[0] / D;
  int E = in_sizes[7];

  char* ws = (char*)d_ws;
  size_t off = 0;
  auto alloc = [&](size_t bytes) -> void* {
    void* p = ws + off;
    off = (off + bytes + 255) & ~(size_t)255;
    return p;
  };
  float* h_buf = (float*)alloc((size_t)N * D * 4);
  float* aggO  = (float*)alloc((size_t)N * D * 4);
  float* aggI  = (float*)alloc((size_t)N * D * 4);
  float* hrA   = (float*)alloc(192 * 4);
  float* hrB   = (float*)alloc(192 * 4);
  int* cnt     = (int*)alloc((size_t)(N + 1) * 4);
  int* cursor  = (int*)alloc((size_t)(N + 1) * 4);
  int* startv  = (int*)alloc((size_t)(N + 1) * 4);
  int* perm    = (int*)alloc((size_t)E * 4);

  // ---- CSR-by-dst build (once per launch) ----
  hipMemsetAsync(cnt, 0, (size_t)N * 4, stream);
  int eb = (E + 255) / 256;
  hist_kernel<<<eb, 256, 0, stream>>>(dst, cnt, E);
  int CH = (N + 1023) / 1024;
  scan_kernel<<<1, 1024, 0, stream>>>(cnt, startv, cursor, N, CH);
  scatter_kernel<<<eb, 256, 0, stream>>>(src, dst, et, edir, cursor, perm, E);

  hr_init_kernel<<<1, 192, 0, stream>>>(alpha, Basis, hrA);
  hipMemcpyAsync(h_buf, h_u, (size_t)N * D * 4, hipMemcpyDeviceToDevice, stream);

  float* hr_cur = hrA;
  float* hr_nxt = hrB;
  int nb_g = (N + 3) / 4;
  int nb_n = (N + 31) / 32;
  for (int l = 0; l < NLAYERS; ++l) {
    gather_kernel<<<nb_g, 256, 0, stream>>>(h_buf, hr_cur, startv, perm, aggO, aggI, N);
    float* outp = (l == NLAYERS - 1) ? (float*)d_out : h_buf;
    node_kernel<<<nb_n, 256, 0, stream>>>(
        h_buf, aggO, aggI,
        W_S + (size_t)l * D * D, W_O + (size_t)l * D * D, W_I + (size_t)l * D * D,
        hr_cur + 2 * D, outp, (l < NLAYERS - 1) ? 1 : 0, N);
    if (l < NLAYERS - 1) {
      hr_update_kernel<<<1, 192, 0, stream>>>(hr_cur, W_rel + (size_t)l * D * D, hr_nxt, 1);
      float* t = hr_cur; hr_cur = hr_nxt; hr_nxt = t;
    }
  }
}

// Round 2
// 1103.423 us; speedup vs baseline: 1.2300x; 1.2300x over previous
//
#include <hip/hip_runtime.h>

constexpr int D = 64;
constexpr int NREL = 2;
constexpr int NBASIS = 16;
constexpr int NLAYERS = 3;
constexpr int SCAN_CHUNK = 1024;   // elements per scan block (256 thr x 4)

// h_r = alpha @ Basis   -> hr[3][64]
__global__ void hr_init_kernel(const float* __restrict__ alpha,
                               const float* __restrict__ basis,
                               float* __restrict__ hr) {
  int t = threadIdx.x;            // 192 threads
  int r = t >> 6, d = t & 63;
  float s = 0.f;
  for (int b = 0; b < NBASIS; ++b) s += alpha[r * NBASIS + b] * basis[b * D + d];
  hr[r * D + d] = s;
}

// h_r = act(h_r @ W_rel.T)
__global__ void hr_update_kernel(const float* __restrict__ hr_in,
                                 const float* __restrict__ Wrel,
                                 float* __restrict__ hr_out, int do_relu) {
  int t = threadIdx.x;            // 192 threads
  int r = t >> 6, d = t & 63;
  float s = 0.f;
  for (int k = 0; k < D; ++k) s += hr_in[r * D + k] * Wrel[d * D + k];
  if (do_relu) s = fmaxf(s, 0.f);
  hr_out[r * D + d] = s;
}

__global__ void hist_kernel(const int* __restrict__ dst, int* __restrict__ cnt, int E) {
  int e = blockIdx.x * blockDim.x + threadIdx.x;
  if (e < E) atomicAdd(&cnt[dst[e]], 1);
}

// ---- parallel 3-phase exclusive scan of cnt[0..N-1] ----
__global__ void scan_partial(const int* __restrict__ cnt, int* __restrict__ bsums, int N) {
  int t = threadIdx.x;
  int base = blockIdx.x * SCAN_CHUNK + t * 4;
  int s = 0;
  if (base + 3 < N) {
    int4 v = *(const int4*)(cnt + base);
    s = v.x + v.y + v.z + v.w;
  } else {
    for (int i = 0; i < 4; ++i) if (base + i < N) s += cnt[base + i];
  }
  for (int off = 32; off > 0; off >>= 1) s += __shfl_down(s, off, 64);
  __shared__ int ws[4];
  if ((t & 63) == 0) ws[t >> 6] = s;
  __syncthreads();
  if (t == 0) bsums[blockIdx.x] = ws[0] + ws[1] + ws[2] + ws[3];
}

// single block, 128 threads; SB <= 128. boffs = exclusive scan of bsums; start[N] = total
__global__ void scan_bsums(const int* __restrict__ bsums, int* __restrict__ boffs,
                           int SB, int* __restrict__ startN) {
  __shared__ int sh[128];
  int t = threadIdx.x;
  int v = (t < SB) ? bsums[t] : 0;
  sh[t] = v;
  __syncthreads();
  for (int off = 1; off < 128; off <<= 1) {
    int u = (t >= off) ? sh[t - off] : 0;
    __syncthreads();
    sh[t] += u;
    __syncthreads();
  }
  if (t < SB) boffs[t] = sh[t] - v;
  if (t == SB - 1) *startN = sh[t];
}

__global__ void scan_final(const int* __restrict__ cnt, const int* __restrict__ boffs,
                           int* __restrict__ start, int* __restrict__ cursor, int N) {
  int t = threadIdx.x;
  int base = blockIdx.x * SCAN_CHUNK + t * 4;
  int v0 = 0, v1 = 0, v2 = 0, v3 = 0;
  if (base + 3 < N) {
    int4 v = *(const int4*)(cnt + base);
    v0 = v.x; v1 = v.y; v2 = v.z; v3 = v.w;
  } else {
    if (base + 0 < N) v0 = cnt[base + 0];
    if (base + 1 < N) v1 = cnt[base + 1];
    if (base + 2 < N) v2 = cnt[base + 2];
    if (base + 3 < N) v3 = cnt[base + 3];
  }
  int ts = v0 + v1 + v2 + v3;
  int lane = t & 63;
  int incl = ts;
  for (int off = 1; off < 64; off <<= 1) {
    int u = __shfl_up(incl, off, 64);
    if (lane >= off) incl += u;
  }
  __shared__ int wsum[4];
  if (lane == 63) wsum[t >> 6] = incl;
  __syncthreads();
  int woff = 0;
  for (int w = 0; w < (t >> 6); ++w) woff += wsum[w];
  int run = boffs[blockIdx.x] + woff + incl - ts;  // exclusive prefix of this thread's 1st elem
  int s0 = run, s1 = run + v0, s2 = s1 + v1, s3 = s2 + v2;
  if (base + 0 < N) { start[base + 0] = s0; cursor[base + 0] = s0; }
  if (base + 1 < N) { start[base + 1] = s1; cursor[base + 1] = s1; }
  if (base + 2 < N) { start[base + 2] = s2; cursor[base + 2] = s2; }
  if (base + 3 < N) { start[base + 3] = s3; cursor[base + 3] = s3; }
}

// perm[p] = src | et<<17 | dir<<18   (src < 2^17)
__global__ void scatter_kernel(const int* __restrict__ src, const int* __restrict__ dst,
                               const int* __restrict__ et, const int* __restrict__ dir,
                               int* __restrict__ cursor, int* __restrict__ perm, int E) {
  int e = blockIdx.x * blockDim.x + threadIdx.x;
  if (e < E) {
    int t = dst[e];
    int p = atomicAdd(&cursor[t], 1);
    perm[p] = src[e] | (et[e] << 17) | (dir[e] << 18);
  }
}

// wave per node: aggO[v], aggI[v] = sum over in-edges of (h[src]-hr[et]) split by dir
__global__ __launch_bounds__(256) void gather_kernel(
    const float* __restrict__ h, const float* __restrict__ hr,
    const int* __restrict__ start, const int* __restrict__ perm,
    float* __restrict__ aggO, float* __restrict__ aggI, int N) {
  int lane = threadIdx.x & 63;
  int v = blockIdx.x * 4 + (threadIdx.x >> 6);
  if (v >= N) return;
  float hr0 = hr[lane];
  float hr1 = hr[D + lane];
  int beg = start[v], end = start[v + 1];
  float accO = 0.f, accI = 0.f;
  for (int j = beg; j < end; ++j) {
    int p = perm[j];
    int s = p & 0x1FFFF;
    float c = h[(size_t)s * D + lane] - (((p >> 17) & 1) ? hr1 : hr0);
    if (p & (1 << 18)) accI += c; else accO += c;
  }
  aggO[(size_t)v * D + lane] = accO;
  aggI[(size_t)v * D + lane] = accI;
}

// h_out[v] = act((h[v]-hr_self)@WS.T + aggO[v]@WO.T + aggI[v]@WI.T)
__global__ __launch_bounds__(256) void node_kernel(
    const float* __restrict__ h_in, const float* __restrict__ aggO,
    const float* __restrict__ aggI, const float* __restrict__ WS,
    const float* __restrict__ WO, const float* __restrict__ WI,
    const float* __restrict__ hr_self, float* __restrict__ h_out,
    int do_relu, int N) {
  __shared__ float4 lws[64 * 17];
  __shared__ float4 lwo[64 * 17];
  __shared__ float4 lwi[64 * 17];
  int tid = threadIdx.x;
  const float4* gws = (const float4*)WS;
  const float4* gwo = (const float4*)WO;
  const float4* gwi = (const float4*)WI;
  for (int i = tid; i < 1024; i += 256) {
    int d = i >> 4, k4 = i & 15;
    lws[d * 17 + k4] = gws[i];
    lwo[d * 17 + k4] = gwo[i];
    lwi[d * 17 + k4] = gwi[i];
  }
  __syncthreads();
  int lane = tid & 63;
  int wid = blockIdx.x * 4 + (tid >> 6);
  const int R = 8;
  int row0 = wid * R;
  if (row0 >= N) return;
  float acc[R];
#pragma unroll
  for (int r = 0; r < R; ++r) acc[r] = 0.f;
  const float4* hr4 = (const float4*)hr_self;
  for (int k4 = 0; k4 < 16; ++k4) {
    float4 ws4 = lws[lane * 17 + k4];
    float4 wo4 = lwo[lane * 17 + k4];
    float4 wi4 = lwi[lane * 17 + k4];
    float4 hs4 = hr4[k4];
#pragma unroll
    for (int r = 0; r < R; ++r) {
      int row = row0 + r;
      if (row < N) {
        const float4 xh = ((const float4*)(h_in + (size_t)row * D))[k4];
        const float4 xo = ((const float4*)(aggO + (size_t)row * D))[k4];
        const float4 xi = ((const float4*)(aggI + (size_t)row * D))[k4];
        acc[r] += (xh.x - hs4.x) * ws4.x + (xh.y - hs4.y) * ws4.y +
                  (xh.z - hs4.z) * ws4.z + (xh.w - hs4.w) * ws4.w +
                  xo.x * wo4.x + xo.y * wo4.y + xo.z * wo4.z + xo.w * wo4.w +
                  xi.x * wi4.x + xi.y * wi4.y + xi.z * wi4.z + xi.w * wi4.w;
      }
    }
  }
#pragma unroll
  for (int r = 0; r < R; ++r) {
    int row = row0 + r;
    if (row < N) {
      float v = acc[r];
      if (do_relu) v = fmaxf(v, 0.f);
      h_out[(size_t)row * D + lane] = v;
    }
  }
}

extern "C" void kernel_launch(void* const* d_in, const int* in_sizes, int n_in,
                              void* d_out, int out_size, void* d_ws, size_t ws_size,
                              hipStream_t stream) {
  const float* h_u   = (const float*)d_in[0];
  const float* Basis = (const float*)d_in[1];
  const float* alpha = (const float*)d_in[2];
  const float* W_O   = (const float*)d_in[3];
  const float* W_I   = (const float*)d_in[4];
  const float* W_S   = (const float*)d_in[5];
  const float* W_rel = (const float*)d_in[6];
  const int* src  = (const int*)d_in[7];
  const int* dst  = (const int*)d_in[8];
  const int* et   = (const int*)d_in[9];
  const int* edir = (const int*)d_in[10];
  int N = in_sizes[0] / D;
  int E = in_sizes[7];

  char* ws = (char*)d_ws;
  size_t off = 0;
  auto alloc = [&](size_t bytes) -> void* {
    void* p = ws + off;
    off = (off + bytes + 255) & ~(size_t)255;
    return p;
  };
  float* h_buf = (float*)alloc((size_t)N * D * 4);
  float* aggO  = (float*)alloc((size_t)N * D * 4);
  float* aggI  = (float*)alloc((size_t)N * D * 4);
  float* hrA   = (float*)alloc(192 * 4);
  float* hrB   = (float*)alloc(192 * 4);
  int* cnt     = (int*)alloc((size_t)(N + 1) * 4);
  int* cursor  = (int*)alloc((size_t)(N + 1) * 4);
  int* startv  = (int*)alloc((size_t)(N + 1) * 4);
  int* perm    = (int*)alloc((size_t)E * 4);
  int SB = (N + SCAN_CHUNK - 1) / SCAN_CHUNK;      // 98 for N=100000
  int* bsums   = (int*)alloc((size_t)SB * 4);
  int* boffs   = (int*)alloc((size_t)SB * 4);

  // ---- CSR-by-dst build (once per launch) ----
  hipMemsetAsync(cnt, 0, (size_t)N * 4, stream);
  int eb = (E + 255) / 256;
  hist_kernel<<<eb, 256, 0, stream>>>(dst, cnt, E);
  scan_partial<<<SB, 256, 0, stream>>>(cnt, bsums, N);
  scan_bsums<<<1, 128, 0, stream>>>(bsums, boffs, SB, startv + N);
  scan_final<<<SB, 256, 0, stream>>>(cnt, boffs, startv, cursor, N);
  scatter_kernel<<<eb, 256, 0, stream>>>(src, dst, et, edir, cursor, perm, E);

  hr_init_kernel<<<1, 192, 0, stream>>>(alpha, Basis, hrA);

  float* hr_cur = hrA;
  float* hr_nxt = hrB;
  int nb_g = (N + 3) / 4;
  int nb_n = (N + 31) / 32;
  for (int l = 0; l < NLAYERS; ++l) {
    const float* h_src = (l == 0) ? h_u : h_buf;
    gather_kernel<<<nb_g, 256, 0, stream>>>(h_src, hr_cur, startv, perm, aggO, aggI, N);
    float* outp = (l == NLAYERS - 1) ? (float*)d_out : h_buf;
    node_kernel<<<nb_n, 256, 0, stream>>>(
        h_src, aggO, aggI,
        W_S + (size_t)l * D * D, W_O + (size_t)l * D * D, W_I + (size_t)l * D * D,
        hr_cur + 2 * D, outp, (l < NLAYERS - 1) ? 1 : 0, N);
    if (l < NLAYERS - 1) {
      hr_update_kernel<<<1, 192, 0, stream>>>(hr_cur, W_rel + (size_t)l * D * D, hr_nxt, 1);
      float* t = hr_cur; hr_cur = hr_nxt; hr_nxt = t;
    }
  }
}

// Round 3
// 816.274 us; speedup vs baseline: 1.6627x; 1.3518x over previous
//
#include <hip/hip_runtime.h>

constexpr int D = 64;
constexpr int NREL = 2;
constexpr int NBASIS = 16;
constexpr int NLAYERS = 3;
constexpr int SCAN_CHUNK = 1024;   // elements per scan block (256 thr x 4)
constexpr int TR = 32;             // rows per node-kernel tile

// h_r = alpha @ Basis   -> hr[3][64]
__global__ void hr_init_kernel(const float* __restrict__ alpha,
                               const float* __restrict__ basis,
                               float* __restrict__ hr) {
  int t = threadIdx.x;            // 192 threads
  int r = t >> 6, d = t & 63;
  float s = 0.f;
  for (int b = 0; b < NBASIS; ++b) s += alpha[r * NBASIS + b] * basis[b * D + d];
  hr[r * D + d] = s;
}

// h_r = act(h_r @ W_rel.T)
__global__ void hr_update_kernel(const float* __restrict__ hr_in,
                                 const float* __restrict__ Wrel,
                                 float* __restrict__ hr_out, int do_relu) {
  int t = threadIdx.x;            // 192 threads
  int r = t >> 6, d = t & 63;
  float s = 0.f;
  for (int k = 0; k < D; ++k) s += hr_in[r * D + k] * Wrel[d * D + k];
  if (do_relu) s = fmaxf(s, 0.f);
  hr_out[r * D + d] = s;
}

__global__ void hist_kernel(const int* __restrict__ dst, int* __restrict__ cnt, int E) {
  int e = blockIdx.x * blockDim.x + threadIdx.x;
  if (e < E) atomicAdd(&cnt[dst[e]], 1);
}

// ---- parallel 3-phase exclusive scan of cnt[0..N-1] ----
__global__ void scan_partial(const int* __restrict__ cnt, int* __restrict__ bsums, int N) {
  int t = threadIdx.x;
  int base = blockIdx.x * SCAN_CHUNK + t * 4;
  int s = 0;
  if (base + 3 < N) {
    int4 v = *(const int4*)(cnt + base);
    s = v.x + v.y + v.z + v.w;
  } else {
    for (int i = 0; i < 4; ++i) if (base + i < N) s += cnt[base + i];
  }
  for (int off = 32; off > 0; off >>= 1) s += __shfl_down(s, off, 64);
  __shared__ int ws[4];
  if ((t & 63) == 0) ws[t >> 6] = s;
  __syncthreads();
  if (t == 0) bsums[blockIdx.x] = ws[0] + ws[1] + ws[2] + ws[3];
}

// single block, 128 threads; SB <= 128. boffs = exclusive scan of bsums; start[N] = total
__global__ void scan_bsums(const int* __restrict__ bsums, int* __restrict__ boffs,
                           int SB, int* __restrict__ startN) {
  __shared__ int sh[128];
  int t = threadIdx.x;
  int v = (t < SB) ? bsums[t] : 0;
  sh[t] = v;
  __syncthreads();
  for (int off = 1; off < 128; off <<= 1) {
    int u = (t >= off) ? sh[t - off] : 0;
    __syncthreads();
    sh[t] += u;
    __syncthreads();
  }
  if (t < SB) boffs[t] = sh[t] - v;
  if (t == SB - 1) *startN = sh[t];
}

__global__ void scan_final(const int* __restrict__ cnt, const int* __restrict__ boffs,
                           int* __restrict__ start, int* __restrict__ cursor, int N) {
  int t = threadIdx.x;
  int base = blockIdx.x * SCAN_CHUNK + t * 4;
  int v0 = 0, v1 = 0, v2 = 0, v3 = 0;
  if (base + 3 < N) {
    int4 v = *(const int4*)(cnt + base);
    v0 = v.x; v1 = v.y; v2 = v.z; v3 = v.w;
  } else {
    if (base + 0 < N) v0 = cnt[base + 0];
    if (base + 1 < N) v1 = cnt[base + 1];
    if (base + 2 < N) v2 = cnt[base + 2];
    if (base + 3 < N) v3 = cnt[base + 3];
  }
  int ts = v0 + v1 + v2 + v3;
  int lane = t & 63;
  int incl = ts;
  for (int off = 1; off < 64; off <<= 1) {
    int u = __shfl_up(incl, off, 64);
    if (lane >= off) incl += u;
  }
  __shared__ int wsum[4];
  if (lane == 63) wsum[t >> 6] = incl;
  __syncthreads();
  int woff = 0;
  for (int w = 0; w < (t >> 6); ++w) woff += wsum[w];
  int run = boffs[blockIdx.x] + woff + incl - ts;  // exclusive prefix of this thread's 1st elem
  int s0 = run, s1 = run + v0, s2 = s1 + v1, s3 = s2 + v2;
  if (base + 0 < N) { start[base + 0] = s0; cursor[base + 0] = s0; }
  if (base + 1 < N) { start[base + 1] = s1; cursor[base + 1] = s1; }
  if (base + 2 < N) { start[base + 2] = s2; cursor[base + 2] = s2; }
  if (base + 3 < N) { start[base + 3] = s3; cursor[base + 3] = s3; }
}

// perm[p] = src | et<<17 | dir<<18   (src < 2^17)
__global__ void scatter_kernel(const int* __restrict__ src, const int* __restrict__ dst,
                               const int* __restrict__ et, const int* __restrict__ dir,
                               int* __restrict__ cursor, int* __restrict__ perm, int E) {
  int e = blockIdx.x * blockDim.x + threadIdx.x;
  if (e < E) {
    int t = dst[e];
    int p = atomicAdd(&cursor[t], 1);
    perm[p] = src[e] | (et[e] << 17) | (dir[e] << 18);
  }
}

// wave per node: aggO[v], aggI[v] = sum over in-edges of (h[src]-hr[et]) split by dir
__global__ __launch_bounds__(256) void gather_kernel(
    const float* __restrict__ h, const float* __restrict__ hr,
    const int* __restrict__ start, const int* __restrict__ perm,
    float* __restrict__ aggO, float* __restrict__ aggI, int N) {
  int lane = threadIdx.x & 63;
  int v = blockIdx.x * 4 + (threadIdx.x >> 6);
  if (v >= N) return;
  float hr0 = hr[lane];
  float hr1 = hr[D + lane];
  int beg = start[v], end = start[v + 1];
  float accO = 0.f, accI = 0.f;
  for (int j = beg; j < end; ++j) {
    int p = perm[j];
    int s = p & 0x1FFFF;
    float c = h[(size_t)s * D + lane] - (((p >> 17) & 1) ? hr1 : hr0);
    if (p & (1 << 18)) accI += c; else accO += c;
  }
  aggO[(size_t)v * D + lane] = accO;
  aggI[(size_t)v * D + lane] = accI;
}

// h_out[v] = act((h[v]-hr_self)@WS.T + aggO[v]@WO.T + aggI[v]@WI.T)
// Tile of TR=32 rows staged in LDS (coalesced float4, -hr_self fused into xh);
// compute reads x via same-address LDS broadcast, W via pad-17 layout (conflict-free).
__global__ __launch_bounds__(256, 2) void node_kernel(
    const float* __restrict__ h_in, const float* __restrict__ aggO,
    const float* __restrict__ aggI, const float* __restrict__ WS,
    const float* __restrict__ WO, const float* __restrict__ WI,
    const float* __restrict__ hr_self, float* __restrict__ h_out,
    int do_relu, int N, int ntiles) {
  __shared__ float4 lws[64 * 17];
  __shared__ float4 lwo[64 * 17];
  __shared__ float4 lwi[64 * 17];
  __shared__ float4 xs[3][TR * 16];
  int tid = threadIdx.x;
  const float4* gws = (const float4*)WS;
  const float4* gwo = (const float4*)WO;
  const float4* gwi = (const float4*)WI;
  for (int i = tid; i < 1024; i += 256) {
    int dd = i >> 4, k4 = i & 15;
    lws[dd * 17 + k4] = gws[i];
    lwo[dd * 17 + k4] = gwo[i];
    lwi[dd * 17 + k4] = gwi[i];
  }
  int lane = tid & 63;
  int wv = tid >> 6;
  const float4* hr4 = (const float4*)hr_self;

  for (int tile = blockIdx.x; tile < ntiles; tile += gridDim.x) {
    int row0 = tile * TR;
    __syncthreads();   // waves done reading xs (and, 1st iter, W staged)
    for (int i = tid; i < TR * 16; i += 256) {
      int r = i >> 4, k4 = i & 15;
      int row = row0 + r;
      if (row < N) {
        size_t base = (size_t)row * 16 + k4;   // float4 index
        float4 xh = ((const float4*)h_in)[base];
        float4 hs = hr4[k4];
        xh.x -= hs.x; xh.y -= hs.y; xh.z -= hs.z; xh.w -= hs.w;
        xs[0][i] = xh;
        xs[1][i] = ((const float4*)aggO)[base];
        xs[2][i] = ((const float4*)aggI)[base];
      }
    }
    __syncthreads();
    float acc[8];
#pragma unroll
    for (int r = 0; r < 8; ++r) acc[r] = 0.f;
    for (int k4 = 0; k4 < 16; ++k4) {
      float4 ws4 = lws[lane * 17 + k4];
      float4 wo4 = lwo[lane * 17 + k4];
      float4 wi4 = lwi[lane * 17 + k4];
#pragma unroll
      for (int r = 0; r < 8; ++r) {
        int lr = (wv * 8 + r) * 16 + k4;
        float4 xh = xs[0][lr];
        float4 xo = xs[1][lr];
        float4 xi = xs[2][lr];
        acc[r] += xh.x * ws4.x + xh.y * ws4.y + xh.z * ws4.z + xh.w * ws4.w +
                  xo.x * wo4.x + xo.y * wo4.y + xo.z * wo4.z + xo.w * wo4.w +
                  xi.x * wi4.x + xi.y * wi4.y + xi.z * wi4.z + xi.w * wi4.w;
      }
    }
#pragma unroll
    for (int r = 0; r < 8; ++r) {
      int row = row0 + wv * 8 + r;
      if (row < N) {
        float v = acc[r];
        if (do_relu) v = fmaxf(v, 0.f);
        h_out[(size_t)row * D + lane] = v;
      }
    }
  }
}

extern "C" void kernel_launch(void* const* d_in, const int* in_sizes, int n_in,
                              void* d_out, int out_size, void* d_ws, size_t ws_size,
                              hipStream_t stream) {
  const float* h_u   = (const float*)d_in[0];
  const float* Basis = (const float*)d_in[1];
  const float* alpha = (const float*)d_in[2];
  const float* W_O   = (const float*)d_in[3];
  const float* W_I   = (const float*)d_in[4];
  const float* W_S   = (const float*)d_in[5];
  const float* W_rel = (const float*)d_in[6];
  const int* src  = (const int*)d_in[7];
  const int* dst  = (const int*)d_in[8];
  const int* et   = (const int*)d_in[9];
  const int* edir = (const int*)d_in[10];
  int N = in_sizes[0] / D;
  int E = in_sizes[7];

  char* ws = (char*)d_ws;
  size_t off = 0;
  auto alloc = [&](size_t bytes) -> void* {
    void* p = ws + off;
    off = (off + bytes + 255) & ~(size_t)255;
    return p;
  };
  float* h_buf = (float*)alloc((size_t)N * D * 4);
  float* aggO  = (float*)alloc((size_t)N * D * 4);
  float* aggI  = (float*)alloc((size_t)N * D * 4);
  float* hrA   = (float*)alloc(192 * 4);
  float* hrB   = (float*)alloc(192 * 4);
  int* cnt     = (int*)alloc((size_t)(N + 1) * 4);
  int* cursor  = (int*)alloc((size_t)(N + 1) * 4);
  int* startv  = (int*)alloc((size_t)(N + 1) * 4);
  int* perm    = (int*)alloc((size_t)E * 4);
  int SB = (N + SCAN_CHUNK - 1) / SCAN_CHUNK;      // 98 for N=100000
  int* bsums   = (int*)alloc((size_t)SB * 4);
  int* boffs   = (int*)alloc((size_t)SB * 4);

  // ---- CSR-by-dst build (once per launch) ----
  hipMemsetAsync(cnt, 0, (size_t)N * 4, stream);
  int eb = (E + 255) / 256;
  hist_kernel<<<eb, 256, 0, stream>>>(dst, cnt, E);
  scan_partial<<<SB, 256, 0, stream>>>(cnt, bsums, N);
  scan_bsums<<<1, 128, 0, stream>>>(bsums, boffs, SB, startv + N);
  scan_final<<<SB, 256, 0, stream>>>(cnt, boffs, startv, cursor, N);
  scatter_kernel<<<eb, 256, 0, stream>>>(src, dst, et, edir, cursor, perm, E);

  hr_init_kernel<<<1, 192, 0, stream>>>(alpha, Basis, hrA);

  float* hr_cur = hrA;
  float* hr_nxt = hrB;
  int nb_g = (N + 3) / 4;
  int ntiles = (N + TR - 1) / TR;       // 3125
  int nb_n = ntiles < 1024 ? ntiles : 1024;
  for (int l = 0; l < NLAYERS; ++l) {
    const float* h_src = (l == 0) ? h_u : h_buf;
    gather_kernel<<<nb_g, 256, 0, stream>>>(h_src, hr_cur, startv, perm, aggO, aggI, N);
    float* outp = (l == NLAYERS - 1) ? (float*)d_out : h_buf;
    node_kernel<<<nb_n, 256, 0, stream>>>(
        h_src, aggO, aggI,
        W_S + (size_t)l * D * D, W_O + (size_t)l * D * D, W_I + (size_t)l * D * D,
        hr_cur + 2 * D, outp, (l < NLAYERS - 1) ? 1 : 0, N, ntiles);
    if (l < NLAYERS - 1) {
      hr_update_kernel<<<1, 192, 0, stream>>>(hr_cur, W_rel + (size_t)l * D * D, hr_nxt, 1);
      float* t = hr_cur; hr_cur = hr_nxt; hr_nxt = t;
    }
  }
}

// Round 5
// 699.197 us; speedup vs baseline: 1.9411x; 1.1674x over previous
//
#include <hip/hip_runtime.h>

constexpr int D = 64;
constexpr int NREL = 2;
constexpr int NBASIS = 16;
constexpr int NLAYERS = 3;
constexpr int SCAN_CHUNK = 1024;   // elements per scan block (256 thr x 4)
constexpr int TR = 32;             // rows per node-kernel tile

// h_r = alpha @ Basis   -> hr[3][64]
__global__ void hr_init_kernel(const float* __restrict__ alpha,
                               const float* __restrict__ basis,
                               float* __restrict__ hr) {
  int t = threadIdx.x;            // 192 threads
  int r = t >> 6, d = t & 63;
  float s = 0.f;
  for (int b = 0; b < NBASIS; ++b) s += alpha[r * NBASIS + b] * basis[b * D + d];
  hr[r * D + d] = s;
}

// h_r = act(h_r @ W_rel.T)
__global__ void hr_update_kernel(const float* __restrict__ hr_in,
                                 const float* __restrict__ Wrel,
                                 float* __restrict__ hr_out, int do_relu) {
  int t = threadIdx.x;            // 192 threads
  int r = t >> 6, d = t & 63;
  float s = 0.f;
  for (int k = 0; k < D; ++k) s += hr_in[r * D + k] * Wrel[d * D + k];
  if (do_relu) s = fmaxf(s, 0.f);
  hr_out[r * D + d] = s;
}

__global__ void hist_kernel(const int* __restrict__ dst, int* __restrict__ cnt, int E) {
  int e = blockIdx.x * blockDim.x + threadIdx.x;
  if (e < E) atomicAdd(&cnt[dst[e]], 1);
}

// ---- parallel 3-phase exclusive scan of cnt[0..N-1] ----
__global__ void scan_partial(const int* __restrict__ cnt, int* __restrict__ bsums, int N) {
  int t = threadIdx.x;
  int base = blockIdx.x * SCAN_CHUNK + t * 4;
  int s = 0;
  if (base + 3 < N) {
    int4 v = *(const int4*)(cnt + base);
    s = v.x + v.y + v.z + v.w;
  } else {
    for (int i = 0; i < 4; ++i) if (base + i < N) s += cnt[base + i];
  }
  for (int off = 32; off > 0; off >>= 1) s += __shfl_down(s, off, 64);
  __shared__ int ws[4];
  if ((t & 63) == 0) ws[t >> 6] = s;
  __syncthreads();
  if (t == 0) bsums[blockIdx.x] = ws[0] + ws[1] + ws[2] + ws[3];
}

// single block, 128 threads; SB <= 128. boffs = exclusive scan of bsums; start[N] = total
__global__ void scan_bsums(const int* __restrict__ bsums, int* __restrict__ boffs,
                           int SB, int* __restrict__ startN) {
  __shared__ int sh[128];
  int t = threadIdx.x;
  int v = (t < SB) ? bsums[t] : 0;
  sh[t] = v;
  __syncthreads();
  for (int off = 1; off < 128; off <<= 1) {
    int u = (t >= off) ? sh[t - off] : 0;
    __syncthreads();
    sh[t] += u;
    __syncthreads();
  }
  if (t < SB) boffs[t] = sh[t] - v;
  if (t == SB - 1) *startN = sh[t];
}

__global__ void scan_final(const int* __restrict__ cnt, const int* __restrict__ boffs,
                           int* __restrict__ start, int* __restrict__ cursor, int N) {
  int t = threadIdx.x;
  int base = blockIdx.x * SCAN_CHUNK + t * 4;
  int v0 = 0, v1 = 0, v2 = 0, v3 = 0;
  if (base + 3 < N) {
    int4 v = *(const int4*)(cnt + base);
    v0 = v.x; v1 = v.y; v2 = v.z; v3 = v.w;
  } else {
    if (base + 0 < N) v0 = cnt[base + 0];
    if (base + 1 < N) v1 = cnt[base + 1];
    if (base + 2 < N) v2 = cnt[base + 2];
    if (base + 3 < N) v3 = cnt[base + 3];
  }
  int ts = v0 + v1 + v2 + v3;
  int lane = t & 63;
  int incl = ts;
  for (int off = 1; off < 64; off <<= 1) {
    int u = __shfl_up(incl, off, 64);
    if (lane >= off) incl += u;
  }
  __shared__ int wsum[4];
  if (lane == 63) wsum[t >> 6] = incl;
  __syncthreads();
  int woff = 0;
  for (int w = 0; w < (t >> 6); ++w) woff += wsum[w];
  int run = boffs[blockIdx.x] + woff + incl - ts;  // exclusive prefix of this thread's 1st elem
  int s0 = run, s1 = run + v0, s2 = s1 + v1, s3 = s2 + v2;
  if (base + 0 < N) { start[base + 0] = s0; cursor[base + 0] = s0; }
  if (base + 1 < N) { start[base + 1] = s1; cursor[base + 1] = s1; }
  if (base + 2 < N) { start[base + 2] = s2; cursor[base + 2] = s2; }
  if (base + 3 < N) { start[base + 3] = s3; cursor[base + 3] = s3; }
}

// perm[p] = src | et<<17 | dir<<18   (src < 2^17)
__global__ void scatter_kernel(const int* __restrict__ src, const int* __restrict__ dst,
                               const int* __restrict__ et, const int* __restrict__ dir,
                               int* __restrict__ cursor, int* __restrict__ perm, int E) {
  int e = blockIdx.x * blockDim.x + threadIdx.x;
  if (e < E) {
    int t = dst[e];
    int p = atomicAdd(&cursor[t], 1);
    perm[p] = src[e] | (et[e] << 17) | (dir[e] << 18);
  }
}

// wave per node: aggO[v], aggI[v] = sum over in-edges of (h[src]-hr[et]) split by dir.
// Edges processed in masked groups of 4: 4 wave-uniform perm loads + 4 independent
// row loads in flight (4-deep MLP breaks the serial load->add chain).
__global__ __launch_bounds__(256) void gather_kernel(
    const float* __restrict__ h, const float* __restrict__ hr,
    const int* __restrict__ start, const int* __restrict__ perm,
    float* __restrict__ aggO, float* __restrict__ aggI, int N) {
  int lane = threadIdx.x & 63;
  int v = blockIdx.x * 4 + (threadIdx.x >> 6);
  if (v >= N) return;
  float hr0 = hr[lane];
  float hr1 = hr[D + lane];
  int beg = start[v], end = start[v + 1];
  float accO = 0.f, accI = 0.f;
  for (int j = beg; j < end; j += 4) {
    // wave-uniform perm words (OOB slots clamp to beg -> cached broadcast)
    int j1 = j + 1 < end ? j + 1 : beg;
    int j2 = j + 2 < end ? j + 2 : beg;
    int j3 = j + 3 < end ? j + 3 : beg;
    int p0 = perm[j];
    int p1 = perm[j1];
    int p2 = perm[j2];
    int p3 = perm[j3];
    // 4 independent row loads
    float f0 = h[(size_t)(p0 & 0x1FFFF) * D + lane];
    float f1 = h[(size_t)(p1 & 0x1FFFF) * D + lane];
    float f2 = h[(size_t)(p2 & 0x1FFFF) * D + lane];
    float f3 = h[(size_t)(p3 & 0x1FFFF) * D + lane];
    // wave-uniform predicated accumulates (order preserved)
    {
      float c = f0 - (((p0 >> 17) & 1) ? hr1 : hr0);
      if (p0 & (1 << 18)) accI += c; else accO += c;
    }
    if (j + 1 < end) {
      float c = f1 - (((p1 >> 17) & 1) ? hr1 : hr0);
      if (p1 & (1 << 18)) accI += c; else accO += c;
    }
    if (j + 2 < end) {
      float c = f2 - (((p2 >> 17) & 1) ? hr1 : hr0);
      if (p2 & (1 << 18)) accI += c; else accO += c;
    }
    if (j + 3 < end) {
      float c = f3 - (((p3 >> 17) & 1) ? hr1 : hr0);
      if (p3 & (1 << 18)) accI += c; else accO += c;
    }
  }
  aggO[(size_t)v * D + lane] = accO;
  aggI[(size_t)v * D + lane] = accI;
}

// h_out[v] = act((h[v]-hr_self)@WS.T + aggO[v]@WO.T + aggI[v]@WI.T)
// Tile of TR=32 rows staged in LDS (coalesced float4, -hr_self fused into xh);
// compute reads x via same-address LDS broadcast, W via pad-17 layout (conflict-free).
__global__ __launch_bounds__(256, 2) void node_kernel(
    const float* __restrict__ h_in, const float* __restrict__ aggO,
    const float* __restrict__ aggI, const float* __restrict__ WS,
    const float* __restrict__ WO, const float* __restrict__ WI,
    const float* __restrict__ hr_self, float* __restrict__ h_out,
    int do_relu, int N, int ntiles) {
  __shared__ float4 lws[64 * 17];
  __shared__ float4 lwo[64 * 17];
  __shared__ float4 lwi[64 * 17];
  __shared__ float4 xs[3][TR * 16];
  int tid = threadIdx.x;
  const float4* gws = (const float4*)WS;
  const float4* gwo = (const float4*)WO;
  const float4* gwi = (const float4*)WI;
  for (int i = tid; i < 1024; i += 256) {
    int dd = i >> 4, k4 = i & 15;
    lws[dd * 17 + k4] = gws[i];
    lwo[dd * 17 + k4] = gwo[i];
    lwi[dd * 17 + k4] = gwi[i];
  }
  int lane = tid & 63;
  int wv = tid >> 6;
  const float4* hr4 = (const float4*)hr_self;

  for (int tile = blockIdx.x; tile < ntiles; tile += gridDim.x) {
    int row0 = tile * TR;
    __syncthreads();   // waves done reading xs (and, 1st iter, W staged)
    for (int i = tid; i < TR * 16; i += 256) {
      int r = i >> 4, k4 = i & 15;
      int row = row0 + r;
      if (row < N) {
        size_t base = (size_t)row * 16 + k4;   // float4 index
        float4 xh = ((const float4*)h_in)[base];
        float4 hs = hr4[k4];
        xh.x -= hs.x; xh.y -= hs.y; xh.z -= hs.z; xh.w -= hs.w;
        xs[0][i] = xh;
        xs[1][i] = ((const float4*)aggO)[base];
        xs[2][i] = ((const float4*)aggI)[base];
      }
    }
    __syncthreads();
    float acc[8];
#pragma unroll
    for (int r = 0; r < 8; ++r) acc[r] = 0.f;
    for (int k4 = 0; k4 < 16; ++k4) {
      float4 ws4 = lws[lane * 17 + k4];
      float4 wo4 = lwo[lane * 17 + k4];
      float4 wi4 = lwi[lane * 17 + k4];
#pragma unroll
      for (int r = 0; r < 8; ++r) {
        int lr = (wv * 8 + r) * 16 + k4;
        float4 xh = xs[0][lr];
        float4 xo = xs[1][lr];
        float4 xi = xs[2][lr];
        acc[r] += xh.x * ws4.x + xh.y * ws4.y + xh.z * ws4.z + xh.w * ws4.w +
                  xo.x * wo4.x + xo.y * wo4.y + xo.z * wo4.z + xo.w * wo4.w +
                  xi.x * wi4.x + xi.y * wi4.y + xi.z * wi4.z + xi.w * wi4.w;
      }
    }
#pragma unroll
    for (int r = 0; r < 8; ++r) {
      int row = row0 + wv * 8 + r;
      if (row < N) {
        float v = acc[r];
        if (do_relu) v = fmaxf(v, 0.f);
        h_out[(size_t)row * D + lane] = v;
      }
    }
  }
}

extern "C" void kernel_launch(void* const* d_in, const int* in_sizes, int n_in,
                              void* d_out, int out_size, void* d_ws, size_t ws_size,
                              hipStream_t stream) {
  const float* h_u   = (const float*)d_in[0];
  const float* Basis = (const float*)d_in[1];
  const float* alpha = (const float*)d_in[2];
  const float* W_O   = (const float*)d_in[3];
  const float* W_I   = (const float*)d_in[4];
  const float* W_S   = (const float*)d_in[5];
  const float* W_rel = (const float*)d_in[6];
  const int* src  = (const int*)d_in[7];
  const int* dst  = (const int*)d_in[8];
  const int* et   = (const int*)d_in[9];
  const int* edir = (const int*)d_in[10];
  int N = in_sizes[0] / D;
  int E = in_sizes[7];

  char* ws = (char*)d_ws;
  size_t off = 0;
  auto alloc = [&](size_t bytes) -> void* {
    void* p = ws + off;
    off = (off + bytes + 255) & ~(size_t)255;
    return p;
  };
  float* h_buf = (float*)alloc((size_t)N * D * 4);
  float* aggO  = (float*)alloc((size_t)N * D * 4);
  float* aggI  = (float*)alloc((size_t)N * D * 4);
  float* hrA   = (float*)alloc(192 * 4);
  float* hrB   = (float*)alloc(192 * 4);
  int* cnt     = (int*)alloc((size_t)(N + 1) * 4);
  int* cursor  = (int*)alloc((size_t)(N + 1) * 4);
  int* startv  = (int*)alloc((size_t)(N + 1) * 4);
  int* perm    = (int*)alloc((size_t)E * 4);
  int SB = (N + SCAN_CHUNK - 1) / SCAN_CHUNK;      // 98 for N=100000
  int* bsums   = (int*)alloc((size_t)SB * 4);
  int* boffs   = (int*)alloc((size_t)SB * 4);

  // ---- CSR-by-dst build (once per launch) ----
  hipMemsetAsync(cnt, 0, (size_t)N * 4, stream);
  int eb = (E + 255) / 256;
  hist_kernel<<<eb, 256, 0, stream>>>(dst, cnt, E);
  scan_partial<<<SB, 256, 0, stream>>>(cnt, bsums, N);
  scan_bsums<<<1, 128, 0, stream>>>(bsums, boffs, SB, startv + N);
  scan_final<<<SB, 256, 0, stream>>>(cnt, boffs, startv, cursor, N);
  scatter_kernel<<<eb, 256, 0, stream>>>(src, dst, et, edir, cursor, perm, E);

  hr_init_kernel<<<1, 192, 0, stream>>>(alpha, Basis, hrA);

  float* hr_cur = hrA;
  float* hr_nxt = hrB;
  int nb_g = (N + 3) / 4;
  int ntiles = (N + TR - 1) / TR;       // 3125
  int nb_n = ntiles < 1024 ? ntiles : 1024;
  for (int l = 0; l < NLAYERS; ++l) {
    const float* h_src = (l == 0) ? h_u : h_buf;
    gather_kernel<<<nb_g, 256, 0, stream>>>(h_src, hr_cur, startv, perm, aggO, aggI, N);
    float* outp = (l == NLAYERS - 1) ? (float*)d_out : h_buf;
    node_kernel<<<nb_n, 256, 0, stream>>>(
        h_src, aggO, aggI,
        W_S + (size_t)l * D * D, W_O + (size_t)l * D * D, W_I + (size_t)l * D * D,
        hr_cur + 2 * D, outp, (l < NLAYERS - 1) ? 1 : 0, N, ntiles);
    if (l < NLAYERS - 1) {
      hr_update_kernel<<<1, 192, 0, stream>>>(hr_cur, W_rel + (size_t)l * D * D, hr_nxt, 1);
      float* t = hr_cur; hr_cur = hr_nxt; hr_nxt = t;
    }
  }
}